// Round 1
// baseline (2978.078 us; speedup 1.0000x reference)
//
#include <hip/hip_runtime.h>
#include <hip/hip_bf16.h>

#define NB 16
#define NN 2048
#define KNNK 16
#define MM 1024
#define RC1 (NB*NN*KNNK)   // 524288 conv1 BN rows
#define RC2 (NB*MM*KNNK)   // 262144 conv2 BN rows

__device__ __forceinline__ float frn_mul(float a, float b){ return __fmul_rn(a,b); }
__device__ __forceinline__ float frn_add(float a, float b){ return __fadd_rn(a,b); }
__device__ __forceinline__ float frn_sub(float a, float b){ return __fsub_rn(a,b); }
__device__ __forceinline__ float silu_f(float x){ return x / (1.0f + __expf(-x)); }

// monotone float->uint mapping (total order == float order, handles negatives)
__device__ __forceinline__ unsigned f32_sortable(float f){
  unsigned u = __float_as_uint(f);
  return u ^ ((unsigned)((int)u >> 31) | 0x80000000u);
}

__device__ __forceinline__ void atomicMaxF(unsigned* addr, float v){
  if (v >= 0.f) atomicMax((int*)addr, (int)__float_as_uint(v));
  else          atomicMin(addr, __float_as_uint(v));
}
__device__ __forceinline__ void atomicMinF(unsigned* addr, float v){
  if (v >= 0.f) atomicMin((int*)addr, (int)__float_as_uint(v));
  else          atomicMax(addr, __float_as_uint(v));
}

__global__ __launch_bounds__(256) void init_kernel(float* stats1, float* stats2a, float* stats2b,
                                                   unsigned* gmax, unsigned* gmin){
  int t = blockIdx.x*256 + threadIdx.x;
  if (t < 128) stats1[t] = 0.f;
  if (t < 256) stats2a[t] = 0.f;
  if (t < 512) stats2b[t] = 0.f;
  if (t < 4096){ gmax[t] = 0xFF800000u; gmin[t] = 0x7F800000u; }  // -inf / +inf bits
}

// ---- knn: one thread per query row, sorted-insert of u64 keys (d,idx) ----
template<int NP>
__global__ __launch_bounds__(256) void knn_kernel(const float* __restrict__ pos, int* __restrict__ idx_out){
  __shared__ float px[NP], py[NP], pz[NP], n2[NP];
  const int bpb = NP / 256;
  int b = blockIdx.x / bpb;
  int rblk = blockIdx.x % bpb;
  const float* pb = pos + (size_t)b * NP * 3;
  for (int i = threadIdx.x; i < NP; i += 256){
    float x = pb[i*3+0], y = pb[i*3+1], z = pb[i*3+2];
    px[i]=x; py[i]=y; pz[i]=z;
    n2[i] = frn_add(frn_add(frn_mul(x,x), frn_mul(y,y)), frn_mul(z,z));
  }
  __syncthreads();
  int i = rblk*256 + threadIdx.x;
  float xi = px[i], yi = py[i], zi = pz[i], n2i = n2[i];
  unsigned long long best[KNNK];
#pragma unroll
  for (int p = 0; p < KNNK; ++p) best[p] = ~0ull;
  for (int j = 0; j < NP; ++j){
    float e = frn_add(frn_add(frn_mul(xi,px[j]), frn_mul(yi,py[j])), frn_mul(zi,pz[j]));
    float d = frn_sub(frn_add(n2i, n2[j]), frn_mul(2.0f, e));
    unsigned long long key = ((unsigned long long)f32_sortable(d) << 32) | (unsigned)j;
    if (key < best[KNNK-1]){
      unsigned long long cur = key;
#pragma unroll
      for (int p = 0; p < KNNK; ++p){
        unsigned long long mn = best[p] < cur ? best[p] : cur;
        unsigned long long mx = best[p] < cur ? cur : best[p];
        best[p] = mn; cur = mx;
      }
    }
  }
  int* op = idx_out + ((size_t)b * NP + i) * KNNK;
#pragma unroll
  for (int p = 0; p < KNNK; ++p) op[p] = (int)(unsigned)(best[p] & 0xFFFFFFFFull);
}

// ---- conv1 stats: wave per row, lane = channel (64) ----
__global__ __launch_bounds__(256) void conv1_stats_kernel(
    const float* __restrict__ pos, const int* __restrict__ idx1,
    const float* __restrict__ W1, const float* __restrict__ b1, float* __restrict__ stats1){
  int lane = threadIdx.x & 63, wv = threadIdx.x >> 6;
  int wave = blockIdx.x*4 + wv;                 // 0..4095, 8 rows each
  float w[6];
#pragma unroll
  for (int f = 0; f < 6; ++f) w[f] = W1[f*64 + lane];
  float bias = b1[lane];
  float ssum = 0.f, ssq = 0.f;
  for (int r = 0; r < 8; ++r){
    int row = wave*8 + r;
    int b = row >> 11, ii = row & 2047;
    const float* pi = pos + ((size_t)(b*NN + ii))*3;
    float xi = pi[0], yi = pi[1], zi = pi[2];
    const int* ip = idx1 + (size_t)row * KNNK;
#pragma unroll 4
    for (int k = 0; k < KNNK; ++k){
      int j = ip[k];
      const float* pj = pos + ((size_t)(b*NN + j))*3;
      float xj = pj[0], yj = pj[1], zj = pj[2];
      float y = bias;
      y = fmaf(xj, w[0], y); y = fmaf(yj, w[1], y); y = fmaf(zj, w[2], y);
      y = fmaf(xj - xi, w[3], y); y = fmaf(yj - yi, w[4], y); y = fmaf(zj - zi, w[5], y);
      ssum += y; ssq = fmaf(y, y, ssq);
    }
  }
  __shared__ float red[4][64][2];
  red[wv][lane][0] = ssum; red[wv][lane][1] = ssq;
  __syncthreads();
  if (threadIdx.x < 64){
    float s = red[0][lane][0]+red[1][lane][0]+red[2][lane][0]+red[3][lane][0];
    float q = red[0][lane][1]+red[1][lane][1]+red[2][lane][1]+red[3][lane][1];
    atomicAdd(&stats1[lane], s);
    atomicAdd(&stats1[64+lane], q);
  }
}

// ---- conv1 apply: recompute y, min/max over K, silu endpoint trick ----
__global__ __launch_bounds__(256) void conv1_apply_kernel(
    const float* __restrict__ pos, const int* __restrict__ idx1,
    const float* __restrict__ W1, const float* __restrict__ b1,
    const float* __restrict__ g1, const float* __restrict__ be1,
    const float* __restrict__ stats1, float* __restrict__ h){
  int lane = threadIdx.x & 63, wv = threadIdx.x >> 6;
  int wave = blockIdx.x*4 + wv;
  float w[6];
#pragma unroll
  for (int f = 0; f < 6; ++f) w[f] = W1[f*64 + lane];
  float bias = b1[lane];
  const float inv = 1.0f / (float)RC1;
  float mu = stats1[lane] * inv;
  float var = fmaxf(stats1[64+lane]*inv - mu*mu, 0.f);
  float sc = rsqrtf(var + 1e-5f) * g1[lane];
  float sh = be1[lane] - mu*sc;
  for (int r = 0; r < 8; ++r){
    int row = wave*8 + r;
    int b = row >> 11, ii = row & 2047;
    const float* pi = pos + ((size_t)(b*NN + ii))*3;
    float xi = pi[0], yi = pi[1], zi = pi[2];
    const int* ip = idx1 + (size_t)row * KNNK;
    float ymn = INFINITY, ymx = -INFINITY;
#pragma unroll 4
    for (int k = 0; k < KNNK; ++k){
      int j = ip[k];
      const float* pj = pos + ((size_t)(b*NN + j))*3;
      float xj = pj[0], yj = pj[1], zj = pj[2];
      float y = bias;
      y = fmaf(xj, w[0], y); y = fmaf(yj, w[1], y); y = fmaf(zj, w[2], y);
      y = fmaf(xj - xi, w[3], y); y = fmaf(yj - yi, w[4], y); y = fmaf(zj - zi, w[5], y);
      ymn = fminf(ymn, y); ymx = fmaxf(ymx, y);
    }
    h[((size_t)row << 6) + lane] = fmaxf(silu_f(fmaf(ymx, sc, sh)), silu_f(fmaf(ymn, sc, sh)));
  }
}

// ---- FPS: one block per batch, serial 1023-step argmax; then gather pos2/hs ----
__global__ __launch_bounds__(256) void fps_kernel(
    const float* __restrict__ pos, const float* __restrict__ h,
    int* __restrict__ idxf, float* __restrict__ pos2, float* __restrict__ hs){
  int b = blockIdx.x, tid = threadIdx.x;
  int lane = tid & 63, wv = tid >> 6;
  __shared__ float px[NN], py[NN], pz[NN];
  __shared__ int sel[MM];
  __shared__ unsigned long long wred[4];
  __shared__ int winner;
  const float* pb = pos + (size_t)b * NN * 3;
  for (int i = tid; i < NN; i += 256){
    px[i] = pb[i*3+0]; py[i] = pb[i*3+1]; pz[i] = pb[i*3+2];
  }
  __syncthreads();
  float qx = px[0], qy = py[0], qz = pz[0];
  float mind[8];
#pragma unroll
  for (int q = 0; q < 8; ++q){
    int p = tid + 256*q;
    float dx = frn_sub(px[p], qx), dy = frn_sub(py[p], qy), dz = frn_sub(pz[p], qz);
    mind[q] = frn_add(frn_add(frn_mul(dx,dx), frn_mul(dy,dy)), frn_mul(dz,dz));
  }
  if (tid == 0) sel[0] = 0;
  for (int s = 1; s < MM; ++s){
    unsigned long long k = 0ull;
#pragma unroll
    for (int q = 0; q < 8; ++q){
      unsigned long long kq = ((unsigned long long)__float_as_uint(mind[q]) << 32)
                              | (unsigned)(~(tid + 256*q));
      k = kq > k ? kq : k;
    }
#pragma unroll
    for (int off = 32; off > 0; off >>= 1){
      unsigned long long o = __shfl_xor(k, off);
      k = o > k ? o : k;
    }
    if (lane == 0) wred[wv] = k;
    __syncthreads();
    if (tid == 0){
      unsigned long long k0 = wred[0] > wred[1] ? wred[0] : wred[1];
      unsigned long long k1 = wred[2] > wred[3] ? wred[2] : wred[3];
      unsigned long long km = k0 > k1 ? k0 : k1;
      int wsel = (int)~(unsigned)km;
      winner = wsel; sel[s] = wsel;
    }
    __syncthreads();
    int wp = winner;
    float wx = px[wp], wy = py[wp], wz = pz[wp];
#pragma unroll
    for (int q = 0; q < 8; ++q){
      int p = tid + 256*q;
      float dx = frn_sub(px[p], wx), dy = frn_sub(py[p], wy), dz = frn_sub(pz[p], wz);
      float d = frn_add(frn_add(frn_mul(dx,dx), frn_mul(dy,dy)), frn_mul(dz,dz));
      mind[q] = fminf(mind[q], d);
    }
  }
  __syncthreads();
  for (int m = tid; m < MM; m += 256){
    int j = sel[m];
    idxf[b*MM + m] = j;
    pos2[((size_t)(b*MM + m))*3 + 0] = px[j];
    pos2[((size_t)(b*MM + m))*3 + 1] = py[j];
    pos2[((size_t)(b*MM + m))*3 + 2] = pz[j];
  }
  for (int t = tid; t < MM*64; t += 256){
    int m = t >> 6, c = t & 63;
    hs[((size_t)(b*MM + m) << 6) + c] = h[((size_t)(b*NN + sel[m]) << 6) + c];
  }
}

// ---- conv2a: wave per row (lane = 2 channels), W2a in LDS; y2a bf16 + stats ----
__global__ __launch_bounds__(256) void conv2a_kernel(
    const float* __restrict__ hs, const float* __restrict__ pos2, const int* __restrict__ idx2,
    const float* __restrict__ W2a, const float* __restrict__ b2a,
    float* __restrict__ stats2a, __hip_bfloat16* __restrict__ y2a){
  __shared__ float Wl[67*128];
  __shared__ float red[4][64][4];
  for (int t = threadIdx.x; t < 67*128; t += 256) Wl[t] = W2a[t];
  __syncthreads();
  int lane = threadIdx.x & 63, wv = threadIdx.x >> 6;
  int wave = blockIdx.x*4 + wv;                 // 0..4095, 64 rows each
  float bias0 = b2a[lane], bias1 = b2a[64+lane];
  float ssum0=0, ssq0=0, ssum1=0, ssq1=0;
  for (int r = 0; r < 64; ++r){
    int row = wave*64 + r;                      // 0..262143
    int b = row >> 14;
    int m = (row >> 4) & 1023;
    int j = idx2[row];
    const float4* hj4 = (const float4*)(hs + ((size_t)(b*MM + j) << 6));
    const float* pm = pos2 + ((size_t)(b*MM + m))*3;
    const float* pj = pos2 + ((size_t)(b*MM + j))*3;
    float y0 = bias0, y1 = bias1;
#pragma unroll
    for (int f4 = 0; f4 < 16; ++f4){
      float4 v = hj4[f4];
      int fb = f4*4;
      y0 = fmaf(v.x, Wl[(fb+0)*128 + lane], y0); y1 = fmaf(v.x, Wl[(fb+0)*128 + 64 + lane], y1);
      y0 = fmaf(v.y, Wl[(fb+1)*128 + lane], y0); y1 = fmaf(v.y, Wl[(fb+1)*128 + 64 + lane], y1);
      y0 = fmaf(v.z, Wl[(fb+2)*128 + lane], y0); y1 = fmaf(v.z, Wl[(fb+2)*128 + 64 + lane], y1);
      y0 = fmaf(v.w, Wl[(fb+3)*128 + lane], y0); y1 = fmaf(v.w, Wl[(fb+3)*128 + 64 + lane], y1);
    }
    float d0 = pj[0]-pm[0], d1 = pj[1]-pm[1], d2 = pj[2]-pm[2];
    y0 = fmaf(d0, Wl[64*128+lane], y0); y1 = fmaf(d0, Wl[64*128+64+lane], y1);
    y0 = fmaf(d1, Wl[65*128+lane], y0); y1 = fmaf(d1, Wl[65*128+64+lane], y1);
    y0 = fmaf(d2, Wl[66*128+lane], y0); y1 = fmaf(d2, Wl[66*128+64+lane], y1);
    ssum0 += y0; ssq0 = fmaf(y0,y0,ssq0);
    ssum1 += y1; ssq1 = fmaf(y1,y1,ssq1);
    y2a[(size_t)row*128 + lane]      = __float2bfloat16(y0);
    y2a[(size_t)row*128 + 64 + lane] = __float2bfloat16(y1);
  }
  red[wv][lane][0]=ssum0; red[wv][lane][1]=ssq0; red[wv][lane][2]=ssum1; red[wv][lane][3]=ssq1;
  __syncthreads();
  if (threadIdx.x < 64){
    float s0=0,q0=0,s1=0,q1=0;
#pragma unroll
    for (int v2=0; v2<4; ++v2){ s0+=red[v2][lane][0]; q0+=red[v2][lane][1]; s1+=red[v2][lane][2]; q1+=red[v2][lane][3]; }
    atomicAdd(&stats2a[lane], s0);      atomicAdd(&stats2a[128+lane], q0);
    atomicAdd(&stats2a[64+lane], s1);   atomicAdd(&stats2a[192+lane], q1);
  }
}

// ---- conv2b: tiled f32 GEMM (32 rows x 64 cols), accumulate stats + per-(b,c) min/max only ----
__global__ __launch_bounds__(256) void conv2b_kernel(
    const __hip_bfloat16* __restrict__ y2a, const float* __restrict__ stats2a,
    const float* __restrict__ g2a, const float* __restrict__ be2a,
    const float* __restrict__ W2b, const float* __restrict__ b2b,
    float* __restrict__ stats2b, unsigned* __restrict__ gmax, unsigned* __restrict__ gmin){
  __shared__ float Wl[128*64];
  __shared__ float aRM[32*133];
  __shared__ float sc2a[128], sh2a[128];
  int tid = threadIdx.x;
  int ct = blockIdx.x & 3;
  int rb = blockIdx.x >> 2;                     // 0..511, 512 rows each
  int c0 = ct * 64;
  for (int t = tid; t < 128*64; t += 256){
    int kk = t >> 6, cc = t & 63;
    Wl[t] = W2b[kk*256 + c0 + cc];
  }
  if (tid < 128){
    const float inv = 1.0f / (float)RC2;
    float mu = stats2a[tid] * inv;
    float var = fmaxf(stats2a[128+tid]*inv - mu*mu, 0.f);
    float s = rsqrtf(var + 1e-5f) * g2a[tid];
    sc2a[tid] = s; sh2a[tid] = be2a[tid] - mu*s;
  }
  int rg = tid >> 4, cg = tid & 15;
  float bb4[4];
#pragma unroll
  for (int j = 0; j < 4; ++j) bb4[j] = b2b[c0 + cg*4 + j];
  float vmn[4], vmx[4], ssum[4], ssq[4];
#pragma unroll
  for (int j = 0; j < 4; ++j){ vmn[j]=INFINITY; vmx[j]=-INFINITY; ssum[j]=0.f; ssq[j]=0.f; }
  int batch = rb >> 5;                          // 512 rows/block, 16384 rows/batch
  const unsigned short* y2u = (const unsigned short*)y2a;
  for (int tile = 0; tile < 16; ++tile){
    int row0 = rb*512 + tile*32;
    __syncthreads();
    for (int t = tid; t < 32*128; t += 256){
      int rr = t >> 7, kk = t & 127;
      float y = __uint_as_float((unsigned)y2u[(size_t)(row0+rr)*128 + kk] << 16);
      aRM[rr*133 + kk] = silu_f(fmaf(y, sc2a[kk], sh2a[kk]));
    }
    __syncthreads();
    float acc[8];
#pragma unroll
    for (int t2 = 0; t2 < 8; ++t2) acc[t2] = 0.f;
    int r0 = rg*2;
#pragma unroll 4
    for (int kk = 0; kk < 128; ++kk){
      float a0 = aRM[r0*133 + kk];
      float a1 = aRM[(r0+1)*133 + kk];
      const float4 w4 = *(const float4*)&Wl[kk*64 + cg*4];
      acc[0] = fmaf(a0, w4.x, acc[0]); acc[1] = fmaf(a0, w4.y, acc[1]);
      acc[2] = fmaf(a0, w4.z, acc[2]); acc[3] = fmaf(a0, w4.w, acc[3]);
      acc[4] = fmaf(a1, w4.x, acc[4]); acc[5] = fmaf(a1, w4.y, acc[5]);
      acc[6] = fmaf(a1, w4.z, acc[6]); acc[7] = fmaf(a1, w4.w, acc[7]);
    }
#pragma unroll
    for (int i = 0; i < 2; ++i)
#pragma unroll
      for (int j = 0; j < 4; ++j){
        float y = acc[i*4+j] + bb4[j];
        vmn[j] = fminf(vmn[j], y); vmx[j] = fmaxf(vmx[j], y);
        ssum[j] += y; ssq[j] = fmaf(y, y, ssq[j]);
      }
  }
  __syncthreads();
  float* scr = aRM;  // reuse as scratch (needs 4096 floats <= 4256)
#pragma unroll
  for (int j = 0; j < 4; ++j){
    scr[((0*16+rg)*16+cg)*4 + j] = vmn[j];
    scr[((1*16+rg)*16+cg)*4 + j] = vmx[j];
    scr[((2*16+rg)*16+cg)*4 + j] = ssum[j];
    scr[((3*16+rg)*16+cg)*4 + j] = ssq[j];
  }
  __syncthreads();
  if (tid < 64){
    int cg_ = tid >> 2, j_ = tid & 3;
    float mn = INFINITY, mx = -INFINITY, s = 0.f, q = 0.f;
    for (int r = 0; r < 16; ++r){
      mn = fminf(mn, scr[((0*16+r)*16+cg_)*4 + j_]);
      mx = fmaxf(mx, scr[((1*16+r)*16+cg_)*4 + j_]);
      s += scr[((2*16+r)*16+cg_)*4 + j_];
      q += scr[((3*16+r)*16+cg_)*4 + j_];
    }
    int c = c0 + cg_*4 + j_;
    atomicAdd(&stats2b[c], s);
    atomicAdd(&stats2b[256+c], q);
    atomicMaxF(&gmax[batch*256 + c], mx);
    atomicMinF(&gmin[batch*256 + c], mn);
  }
}

__global__ __launch_bounds__(256) void final_kernel(
    const float* __restrict__ stats2b, const unsigned* __restrict__ gmax,
    const unsigned* __restrict__ gmin, const float* __restrict__ g2b,
    const float* __restrict__ be2b, float* __restrict__ out){
  int t = blockIdx.x*256 + threadIdx.x;
  if (t >= NB*256) return;
  int c = t & 255;
  const float inv = 1.0f / (float)RC2;
  float mu = stats2b[c]*inv;
  float var = fmaxf(stats2b[256+c]*inv - mu*mu, 0.f);
  float sc = rsqrtf(var + 1e-5f)*g2b[c];
  float sh = be2b[c] - mu*sc;
  float mx = __uint_as_float(gmax[t]);
  float mn = __uint_as_float(gmin[t]);
  out[t] = fmaxf(silu_f(fmaf(mx, sc, sh)), silu_f(fmaf(mn, sc, sh)));
}

extern "C" void kernel_launch(void* const* d_in, const int* in_sizes, int n_in,
                              void* d_out, int out_size, void* d_ws, size_t ws_size,
                              hipStream_t stream){
  (void)in_sizes; (void)n_in; (void)out_size; (void)ws_size;
  const float* pos  = (const float*)d_in[0];
  const float* W1   = (const float*)d_in[1];
  const float* b1   = (const float*)d_in[2];
  const float* g1   = (const float*)d_in[3];
  const float* be1  = (const float*)d_in[4];
  const float* W2a  = (const float*)d_in[5];
  const float* b2a  = (const float*)d_in[6];
  const float* g2a  = (const float*)d_in[7];
  const float* be2a = (const float*)d_in[8];
  const float* W2b  = (const float*)d_in[9];
  const float* b2b  = (const float*)d_in[10];
  const float* g2b  = (const float*)d_in[11];
  const float* be2b = (const float*)d_in[12];

  char* w = (char*)d_ws;
  size_t off = 0;
  auto carve = [&](size_t bytes)->void*{ void* p = w + off; off += (bytes + 255) & ~(size_t)255; return p; };
  int*      idx1    = (int*)carve((size_t)RC1*4/KNNK*KNNK*4/4);  // 524288 ints
  float*    h       = (float*)carve((size_t)NB*NN*64*4);
  int*      idxf    = (int*)carve((size_t)NB*MM*4);
  float*    pos2    = (float*)carve((size_t)NB*MM*3*4);
  float*    hs      = (float*)carve((size_t)NB*MM*64*4);
  int*      idx2    = (int*)carve((size_t)RC2*4);
  float*    stats1  = (float*)carve(128*4);
  float*    stats2a = (float*)carve(256*4);
  float*    stats2b = (float*)carve(512*4);
  unsigned* gmax    = (unsigned*)carve(4096*4);
  unsigned* gmin    = (unsigned*)carve(4096*4);
  __hip_bfloat16* y2a = (__hip_bfloat16*)carve((size_t)RC2*128*2);

  init_kernel<<<dim3(16), dim3(256), 0, stream>>>(stats1, stats2a, stats2b, gmax, gmin);
  knn_kernel<2048><<<dim3(128), dim3(256), 0, stream>>>(pos, idx1);
  conv1_stats_kernel<<<dim3(1024), dim3(256), 0, stream>>>(pos, idx1, W1, b1, stats1);
  conv1_apply_kernel<<<dim3(1024), dim3(256), 0, stream>>>(pos, idx1, W1, b1, g1, be1, stats1, h);
  fps_kernel<<<dim3(16), dim3(256), 0, stream>>>(pos, h, idxf, pos2, hs);
  knn_kernel<1024><<<dim3(64), dim3(256), 0, stream>>>(pos2, idx2);
  conv2a_kernel<<<dim3(1024), dim3(256), 0, stream>>>(hs, pos2, idx2, W2a, b2a, stats2a, y2a);
  conv2b_kernel<<<dim3(2048), dim3(256), 0, stream>>>(y2a, stats2a, g2a, be2a, W2b, b2b, stats2b, gmax, gmin);
  final_kernel<<<dim3(16), dim3(256), 0, stream>>>(stats2b, gmax, gmin, g2b, be2b, (float*)d_out);
}

// Round 3
// 1412.019 us; speedup vs baseline: 2.1091x; 2.1091x over previous
//
#include <hip/hip_runtime.h>
#include <hip/hip_bf16.h>

#define NB 16
#define NN 2048
#define KNNK 16
#define MM 1024
#define RC1 (NB*NN*KNNK)   // 524288 conv1 BN rows
#define RC2 (NB*MM*KNNK)   // 262144 conv2 BN rows

typedef unsigned long long u64;

__device__ __forceinline__ float frn_mul(float a, float b){ return __fmul_rn(a,b); }
__device__ __forceinline__ float frn_add(float a, float b){ return __fadd_rn(a,b); }
__device__ __forceinline__ float frn_sub(float a, float b){ return __fsub_rn(a,b); }
__device__ __forceinline__ float silu_f(float x){ return x / (1.0f + __expf(-x)); }

__device__ __forceinline__ unsigned f32_sortable(float f){
  unsigned u = __float_as_uint(f);
  return u ^ ((unsigned)((int)u >> 31) | 0x80000000u);
}

__device__ __forceinline__ void atomicMaxF(unsigned* addr, float v){
  if (v >= 0.f) atomicMax((int*)addr, (int)__float_as_uint(v));
  else          atomicMin(addr, __float_as_uint(v));
}
__device__ __forceinline__ void atomicMinF(unsigned* addr, float v){
  if (v >= 0.f) atomicMin((int*)addr, (int)__float_as_uint(v));
  else          atomicMax(addr, __float_as_uint(v));
}

__global__ __launch_bounds__(256) void init_kernel(float* stats1, float* stats2a, float* stats2b,
                                                   unsigned* gmax, unsigned* gmin){
  int t = blockIdx.x*256 + threadIdx.x;
  if (t < 128) stats1[t] = 0.f;
  if (t < 256) stats2a[t] = 0.f;
  if (t < 512) stats2b[t] = 0.f;
  if (t < 4096){ gmax[t] = 0xFF800000u; gmin[t] = 0x7F800000u; }
}

// ---- knn chunk: 256 query threads vs CHUNK staged points; sorted u64 top-16 ----
template<int CHUNK>
__device__ __forceinline__ void knn_chunk_body(const float* __restrict__ pos_b, int qbase, int jbase,
                                               float4* sm, u64* __restrict__ out, int tid){
  for (int t = tid; t < CHUNK; t += 256){
    const float* p = pos_b + (size_t)(jbase + t)*3;
    float x = p[0], y = p[1], z = p[2];
    float n2 = frn_add(frn_add(frn_mul(x,x), frn_mul(y,y)), frn_mul(z,z));
    sm[t] = make_float4(x,y,z,n2);
  }
  __syncthreads();
  int i = qbase + tid;
  const float* qp = pos_b + (size_t)i*3;
  float xi = qp[0], yi = qp[1], zi = qp[2];
  float n2i = frn_add(frn_add(frn_mul(xi,xi), frn_mul(yi,yi)), frn_mul(zi,zi));
  u64 best[KNNK];
#pragma unroll
  for (int p = 0; p < KNNK; ++p) best[p] = ~0ull;
  for (int jj = 0; jj < CHUNK; ++jj){
    float4 v = sm[jj];
    float e = frn_add(frn_add(frn_mul(xi,v.x), frn_mul(yi,v.y)), frn_mul(zi,v.z));
    float d = frn_sub(frn_add(n2i, v.w), frn_mul(2.0f, e));
    u64 key = ((u64)f32_sortable(d) << 32) | (unsigned)(jbase + jj);
    if (key < best[KNNK-1]){
      u64 cur = key;
#pragma unroll
      for (int p = 0; p < KNNK; ++p){
        u64 mn = best[p] < cur ? best[p] : cur;
        u64 mx = best[p] < cur ? cur : best[p];
        best[p] = mn; cur = mx;
      }
    }
  }
#pragma unroll
  for (int p = 0; p < KNNK; ++p) out[p] = best[p];
}

// ---- K0: blocks 0..15 = FPS (index-only), blocks 16..271 = knn1 chunks ----
__global__ __launch_bounds__(256) void k0_fps_knn1(const float* __restrict__ pos,
    int* __restrict__ idxf, float* __restrict__ pos2, u64* __restrict__ pknn1){
  __shared__ __align__(16) char smem[29*1024];
  int tid = threadIdx.x;
  if (blockIdx.x < 16){
    int b = blockIdx.x;
    float* px = (float*)smem;
    float* py = px + NN;
    float* pz = py + NN;
    int* sel = (int*)(pz + NN);
    u64* wred = (u64*)(sel + MM);       // [2][4]
    const float* pb = pos + (size_t)b*NN*3;
    for (int i = tid; i < NN; i += 256){
      px[i] = pb[i*3+0]; py[i] = pb[i*3+1]; pz[i] = pb[i*3+2];
    }
    __syncthreads();
    float qx = px[0], qy = py[0], qz = pz[0];
    float mind[8];
#pragma unroll
    for (int q = 0; q < 8; ++q){
      int p = tid + 256*q;
      float dx = frn_sub(px[p],qx), dy = frn_sub(py[p],qy), dz = frn_sub(pz[p],qz);
      mind[q] = frn_add(frn_add(frn_mul(dx,dx), frn_mul(dy,dy)), frn_mul(dz,dz));
    }
    if (tid == 0) sel[0] = 0;
    int lane = tid & 63, wv = tid >> 6;
    for (int s = 1; s < MM; ++s){
      u64 k = 0;
#pragma unroll
      for (int q = 0; q < 8; ++q){
        u64 kq = ((u64)__float_as_uint(mind[q]) << 32) | (unsigned)(~(tid + 256*q));
        k = kq > k ? kq : k;
      }
#pragma unroll
      for (int off = 32; off > 0; off >>= 1){
        u64 o = __shfl_xor(k, off);
        k = o > k ? o : k;
      }
      if (lane == 0) wred[(s&1)*4 + wv] = k;
      __syncthreads();
      u64 k0 = wred[(s&1)*4+0], k1 = wred[(s&1)*4+1];
      u64 k2 = wred[(s&1)*4+2], k3 = wred[(s&1)*4+3];
      k0 = k0 > k1 ? k0 : k1; k2 = k2 > k3 ? k2 : k3;
      u64 km = k0 > k2 ? k0 : k2;
      int wp = (int)~(unsigned)km;
      if (tid == 0) sel[s] = wp;
      float wx = px[wp], wy = py[wp], wz = pz[wp];
#pragma unroll
      for (int q = 0; q < 8; ++q){
        int p = tid + 256*q;
        float dx = frn_sub(px[p],wx), dy = frn_sub(py[p],wy), dz = frn_sub(pz[p],wz);
        float d = frn_add(frn_add(frn_mul(dx,dx), frn_mul(dy,dy)), frn_mul(dz,dz));
        mind[q] = fminf(mind[q], d);
      }
    }
    __syncthreads();
    for (int m = tid; m < MM; m += 256){
      int j = sel[m];
      idxf[b*MM + m] = j;
      pos2[((size_t)(b*MM+m))*3+0] = px[j];
      pos2[((size_t)(b*MM+m))*3+1] = py[j];
      pos2[((size_t)(b*MM+m))*3+2] = pz[j];
    }
  } else {
    int cid = blockIdx.x - 16;          // 0..255
    int b = cid >> 4;
    int rblk = (cid >> 1) & 7;
    int ch = cid & 1;
    float4* sm = (float4*)smem;         // 1024 * 16B
    const float* pos_b = pos + (size_t)b*NN*3;
    int i = rblk*256 + tid;
    u64* out = pknn1 + ((size_t)(b*NN + i)*2 + ch)*KNNK;
    knn_chunk_body<1024>(pos_b, rblk*256, ch*1024, sm, out, tid);
  }
}

// ---- K1: blocks 0..127 = merge1 (2-way), blocks 128..383 = knn2 chunks ----
__global__ __launch_bounds__(256) void k1_merge1_knn2(const u64* __restrict__ pknn1,
    int* __restrict__ idx1, const float* __restrict__ pos2, u64* __restrict__ pknn2){
  __shared__ __align__(16) float4 sm[256];
  int tid = threadIdx.x;
  if (blockIdx.x < 128){
    int row = blockIdx.x*256 + tid;     // 32768 rows
    const u64* A = pknn1 + (size_t)row*32;
    const u64* B = A + 16;
    int ia = 0, ib = 0;
    int* op = idx1 + (size_t)row*KNNK;
#pragma unroll
    for (int p = 0; p < KNNK; ++p){
      u64 ka = A[ia], kb = B[ib];
      if (ka < kb){ op[p] = (int)(unsigned)ka; ++ia; }
      else        { op[p] = (int)(unsigned)kb; ++ib; }
    }
  } else {
    int cid = blockIdx.x - 128;         // 0..255
    int b = cid >> 4;
    int rblk = (cid >> 2) & 3;
    int ch = cid & 3;
    const float* pos_b = pos2 + (size_t)b*MM*3;
    int i = rblk*256 + tid;
    u64* out = pknn2 + ((size_t)(b*MM + i)*4 + ch)*KNNK;
    knn_chunk_body<256>(pos_b, rblk*256, ch*256, sm, out, tid);
  }
}

// ---- K2: blocks 0..63 = merge2 (4-way), blocks 64..1087 = conv1 stats ----
__global__ __launch_bounds__(256) void k2_merge2_c1stats(const u64* __restrict__ pknn2,
    int* __restrict__ idx2, const float* __restrict__ pos, const int* __restrict__ idx1,
    const float* __restrict__ W1, const float* __restrict__ b1, float* __restrict__ stats1){
  __shared__ float red[4][64][2];
  int tid = threadIdx.x;
  if (blockIdx.x < 64){
    int row = blockIdx.x*256 + tid;     // 16384 rows
    const u64* L = pknn2 + (size_t)row*64;
    int o0=0, o1=0, o2=0, o3=0;
    int* op = idx2 + (size_t)row*KNNK;
#pragma unroll
    for (int p = 0; p < KNNK; ++p){
      u64 k0 = L[o0], k1 = L[16+o1], k2 = L[32+o2], k3 = L[48+o3];
      u64 m01 = k0 < k1 ? k0 : k1;
      u64 m23 = k2 < k3 ? k2 : k3;
      u64 m = m01 < m23 ? m01 : m23;
      op[p] = (int)(unsigned)m;
      o0 += (m == k0); o1 += (m == k1); o2 += (m == k2); o3 += (m == k3);
    }
    return;
  }
  int lane = tid & 63, wv = tid >> 6;
  int wave = (blockIdx.x - 64)*4 + wv;  // 0..4095, 8 rows each
  float w[6];
#pragma unroll
  for (int f = 0; f < 6; ++f) w[f] = W1[f*64 + lane];
  float bias = b1[lane];
  float ssum = 0.f, ssq = 0.f;
  for (int r = 0; r < 8; ++r){
    int row = wave*8 + r;
    int b = row >> 11, ii = row & 2047;
    const float* pi = pos + ((size_t)(b*NN + ii))*3;
    float xi = pi[0], yi = pi[1], zi = pi[2];
    const int* ip = idx1 + (size_t)row * KNNK;
#pragma unroll 4
    for (int k = 0; k < KNNK; ++k){
      int j = ip[k];
      const float* pj = pos + ((size_t)(b*NN + j))*3;
      float xj = pj[0], yj = pj[1], zj = pj[2];
      float y = bias;
      y = fmaf(xj, w[0], y); y = fmaf(yj, w[1], y); y = fmaf(zj, w[2], y);
      y = fmaf(xj - xi, w[3], y); y = fmaf(yj - yi, w[4], y); y = fmaf(zj - zi, w[5], y);
      ssum += y; ssq = fmaf(y, y, ssq);
    }
  }
  red[wv][lane][0] = ssum; red[wv][lane][1] = ssq;
  __syncthreads();
  if (tid < 64){
    float s = red[0][lane][0]+red[1][lane][0]+red[2][lane][0]+red[3][lane][0];
    float q = red[0][lane][1]+red[1][lane][1]+red[2][lane][1]+red[3][lane][1];
    atomicAdd(&stats1[lane], s);
    atomicAdd(&stats1[64+lane], q);
  }
}

__global__ __launch_bounds__(256) void conv1_apply_kernel(
    const float* __restrict__ pos, const int* __restrict__ idx1,
    const float* __restrict__ W1, const float* __restrict__ b1,
    const float* __restrict__ g1, const float* __restrict__ be1,
    const float* __restrict__ stats1, float* __restrict__ h){
  int lane = threadIdx.x & 63, wv = threadIdx.x >> 6;
  int wave = blockIdx.x*4 + wv;
  float w[6];
#pragma unroll
  for (int f = 0; f < 6; ++f) w[f] = W1[f*64 + lane];
  float bias = b1[lane];
  const float inv = 1.0f / (float)RC1;
  float mu = stats1[lane] * inv;
  float var = fmaxf(stats1[64+lane]*inv - mu*mu, 0.f);
  float sc = rsqrtf(var + 1e-5f) * g1[lane];
  float sh = be1[lane] - mu*sc;
  for (int r = 0; r < 8; ++r){
    int row = wave*8 + r;
    int b = row >> 11, ii = row & 2047;
    const float* pi = pos + ((size_t)(b*NN + ii))*3;
    float xi = pi[0], yi = pi[1], zi = pi[2];
    const int* ip = idx1 + (size_t)row * KNNK;
    float ymn = INFINITY, ymx = -INFINITY;
#pragma unroll 4
    for (int k = 0; k < KNNK; ++k){
      int j = ip[k];
      const float* pj = pos + ((size_t)(b*NN + j))*3;
      float xj = pj[0], yj = pj[1], zj = pj[2];
      float y = bias;
      y = fmaf(xj, w[0], y); y = fmaf(yj, w[1], y); y = fmaf(zj, w[2], y);
      y = fmaf(xj - xi, w[3], y); y = fmaf(yj - yi, w[4], y); y = fmaf(zj - zi, w[5], y);
      ymn = fminf(ymn, y); ymx = fmaxf(ymx, y);
    }
    h[((size_t)row << 6) + lane] = fmaxf(silu_f(fmaf(ymx, sc, sh)), silu_f(fmaf(ymn, sc, sh)));
  }
}

// ---- conv2a: 4 rows share each LDS weight read; double indirection replaces hs ----
__global__ __launch_bounds__(256) void conv2a_kernel(
    const float* __restrict__ h, const int* __restrict__ idxf,
    const float* __restrict__ pos2, const int* __restrict__ idx2,
    const float* __restrict__ W2a, const float* __restrict__ b2a,
    float* __restrict__ stats2a, __hip_bfloat16* __restrict__ y2a){
  __shared__ float Wl[67*128];
  __shared__ float red[4][64][4];
  for (int t = threadIdx.x; t < 67*128; t += 256) Wl[t] = W2a[t];
  __syncthreads();
  int lane = threadIdx.x & 63, wv = threadIdx.x >> 6;
  int wave = blockIdx.x*4 + wv;                 // 0..4095, 64 rows each
  float bias0 = b2a[lane], bias1 = b2a[64+lane];
  float ssum0=0, ssq0=0, ssum1=0, ssq1=0;
  for (int r4 = 0; r4 < 16; ++r4){
    int row0 = wave*64 + r4*4;
    int b = row0 >> 14;
    int m = (row0 >> 4) & 1023;
    int j0 = idx2[row0+0], j1 = idx2[row0+1], j2 = idx2[row0+2], j3 = idx2[row0+3];
    int q0 = idxf[b*MM + j0], q1 = idxf[b*MM + j1], q2 = idxf[b*MM + j2], q3 = idxf[b*MM + j3];
    const float4* h0 = (const float4*)(h + ((size_t)(b*NN + q0) << 6));
    const float4* h1 = (const float4*)(h + ((size_t)(b*NN + q1) << 6));
    const float4* h2 = (const float4*)(h + ((size_t)(b*NN + q2) << 6));
    const float4* h3 = (const float4*)(h + ((size_t)(b*NN + q3) << 6));
    float y00=bias0, y01=bias1, y10=bias0, y11=bias1;
    float y20=bias0, y21=bias1, y30=bias0, y31=bias1;
#define C2A_STEP(e, a0v, a1v, a2v, a3v) { \
      float w0_ = Wl[(e)*128 + lane], w1_ = Wl[(e)*128 + 64 + lane]; \
      y00 = fmaf(a0v, w0_, y00); y01 = fmaf(a0v, w1_, y01); \
      y10 = fmaf(a1v, w0_, y10); y11 = fmaf(a1v, w1_, y11); \
      y20 = fmaf(a2v, w0_, y20); y21 = fmaf(a2v, w1_, y21); \
      y30 = fmaf(a3v, w0_, y30); y31 = fmaf(a3v, w1_, y31); }
#pragma unroll
    for (int f4 = 0; f4 < 16; ++f4){
      float4 v0 = h0[f4], v1 = h1[f4], v2 = h2[f4], v3 = h3[f4];
      C2A_STEP(f4*4+0, v0.x, v1.x, v2.x, v3.x)
      C2A_STEP(f4*4+1, v0.y, v1.y, v2.y, v3.y)
      C2A_STEP(f4*4+2, v0.z, v1.z, v2.z, v3.z)
      C2A_STEP(f4*4+3, v0.w, v1.w, v2.w, v3.w)
    }
    const float* pm = pos2 + ((size_t)(b*MM + m))*3;
    float pmx = pm[0], pmy = pm[1], pmz = pm[2];
    const float* pj0 = pos2 + ((size_t)(b*MM + j0))*3;
    const float* pj1 = pos2 + ((size_t)(b*MM + j1))*3;
    const float* pj2 = pos2 + ((size_t)(b*MM + j2))*3;
    const float* pj3 = pos2 + ((size_t)(b*MM + j3))*3;
    C2A_STEP(64, pj0[0]-pmx, pj1[0]-pmx, pj2[0]-pmx, pj3[0]-pmx)
    C2A_STEP(65, pj0[1]-pmy, pj1[1]-pmy, pj2[1]-pmy, pj3[1]-pmy)
    C2A_STEP(66, pj0[2]-pmz, pj1[2]-pmz, pj2[2]-pmz, pj3[2]-pmz)
#undef C2A_STEP
    ssum0 += y00+y10+y20+y30;
    ssum1 += y01+y11+y21+y31;
    ssq0 = fmaf(y00,y00,fmaf(y10,y10,fmaf(y20,y20,fmaf(y30,y30,ssq0))));
    ssq1 = fmaf(y01,y01,fmaf(y11,y11,fmaf(y21,y21,fmaf(y31,y31,ssq1))));
    y2a[(size_t)(row0+0)*128 + lane]      = __float2bfloat16(y00);
    y2a[(size_t)(row0+0)*128 + 64 + lane] = __float2bfloat16(y01);
    y2a[(size_t)(row0+1)*128 + lane]      = __float2bfloat16(y10);
    y2a[(size_t)(row0+1)*128 + 64 + lane] = __float2bfloat16(y11);
    y2a[(size_t)(row0+2)*128 + lane]      = __float2bfloat16(y20);
    y2a[(size_t)(row0+2)*128 + 64 + lane] = __float2bfloat16(y21);
    y2a[(size_t)(row0+3)*128 + lane]      = __float2bfloat16(y30);
    y2a[(size_t)(row0+3)*128 + 64 + lane] = __float2bfloat16(y31);
  }
  red[wv][lane][0]=ssum0; red[wv][lane][1]=ssq0; red[wv][lane][2]=ssum1; red[wv][lane][3]=ssq1;
  __syncthreads();
  if (threadIdx.x < 64){
    float s0=0,q0=0,s1=0,q1=0;
#pragma unroll
    for (int v2=0; v2<4; ++v2){ s0+=red[v2][lane][0]; q0+=red[v2][lane][1]; s1+=red[v2][lane][2]; q1+=red[v2][lane][3]; }
    atomicAdd(&stats2a[lane], s0);      atomicAdd(&stats2a[128+lane], q0);
    atomicAdd(&stats2a[64+lane], s1);   atomicAdd(&stats2a[192+lane], q1);
  }
}

// ---- conv2b: 64x64 tiles, transposed activation staging, 4x4 thread tile ----
__global__ __launch_bounds__(256) void conv2b_kernel(
    const __hip_bfloat16* __restrict__ y2a, const float* __restrict__ stats2a,
    const float* __restrict__ g2a, const float* __restrict__ be2a,
    const float* __restrict__ W2b, const float* __restrict__ b2b,
    float* __restrict__ stats2b, unsigned* __restrict__ gmax, unsigned* __restrict__ gmin){
  __shared__ float Wl[128*64];
  __shared__ float aT[128*64];
  __shared__ float sc2a[128], sh2a[128];
  int tid = threadIdx.x;
  int ct = blockIdx.x & 3;
  int rb = blockIdx.x >> 2;                     // 0..511, 512 rows each
  int c0 = ct * 64;
  for (int t = tid; t < 128*64; t += 256){
    int kk = t >> 6, cc = t & 63;
    Wl[t] = W2b[kk*256 + c0 + cc];
  }
  if (tid < 128){
    const float inv = 1.0f / (float)RC2;
    float mu = stats2a[tid] * inv;
    float var = fmaxf(stats2a[128+tid]*inv - mu*mu, 0.f);
    float s = rsqrtf(var + 1e-5f) * g2a[tid];
    sc2a[tid] = s; sh2a[tid] = be2a[tid] - mu*s;
  }
  __syncthreads();
  int rg = tid & 15, cg = tid >> 4;
  float bb4[4];
#pragma unroll
  for (int j = 0; j < 4; ++j) bb4[j] = b2b[c0 + cg*4 + j];
  float vmn[4], vmx[4], ssum[4], ssq[4];
#pragma unroll
  for (int j = 0; j < 4; ++j){ vmn[j]=INFINITY; vmx[j]=-INFINITY; ssum[j]=0.f; ssq[j]=0.f; }
  int batch = rb >> 5;
  const unsigned short* y2u = (const unsigned short*)y2a;
  int srr = tid & 63, skq = tid >> 6;           // staging: row = srr, k-quarter = skq
  for (int tile = 0; tile < 8; ++tile){
    int row0 = rb*512 + tile*64;
    const unsigned short* src = y2u + (size_t)(row0 + srr)*128 + skq*32;
#pragma unroll
    for (int u = 0; u < 8; ++u){
      ushort4 v = *(const ushort4*)(src + u*4);
      int kk = skq*32 + u*4;
      float f0 = __uint_as_float((unsigned)v.x << 16);
      float f1 = __uint_as_float((unsigned)v.y << 16);
      float f2 = __uint_as_float((unsigned)v.z << 16);
      float f3 = __uint_as_float((unsigned)v.w << 16);
      aT[(kk+0)*64 + srr] = silu_f(fmaf(f0, sc2a[kk+0], sh2a[kk+0]));
      aT[(kk+1)*64 + srr] = silu_f(fmaf(f1, sc2a[kk+1], sh2a[kk+1]));
      aT[(kk+2)*64 + srr] = silu_f(fmaf(f2, sc2a[kk+2], sh2a[kk+2]));
      aT[(kk+3)*64 + srr] = silu_f(fmaf(f3, sc2a[kk+3], sh2a[kk+3]));
    }
    __syncthreads();
    float acc[4][4];
#pragma unroll
    for (int i = 0; i < 4; ++i)
#pragma unroll
      for (int j = 0; j < 4; ++j) acc[i][j] = 0.f;
#pragma unroll 4
    for (int kk = 0; kk < 128; ++kk){
      float4 av = *(const float4*)&aT[kk*64 + rg*4];
      float4 wv4 = *(const float4*)&Wl[kk*64 + cg*4];
      acc[0][0]=fmaf(av.x,wv4.x,acc[0][0]); acc[0][1]=fmaf(av.x,wv4.y,acc[0][1]);
      acc[0][2]=fmaf(av.x,wv4.z,acc[0][2]); acc[0][3]=fmaf(av.x,wv4.w,acc[0][3]);
      acc[1][0]=fmaf(av.y,wv4.x,acc[1][0]); acc[1][1]=fmaf(av.y,wv4.y,acc[1][1]);
      acc[1][2]=fmaf(av.y,wv4.z,acc[1][2]); acc[1][3]=fmaf(av.y,wv4.w,acc[1][3]);
      acc[2][0]=fmaf(av.z,wv4.x,acc[2][0]); acc[2][1]=fmaf(av.z,wv4.y,acc[2][1]);
      acc[2][2]=fmaf(av.z,wv4.z,acc[2][2]); acc[2][3]=fmaf(av.z,wv4.w,acc[2][3]);
      acc[3][0]=fmaf(av.w,wv4.x,acc[3][0]); acc[3][1]=fmaf(av.w,wv4.y,acc[3][1]);
      acc[3][2]=fmaf(av.w,wv4.z,acc[3][2]); acc[3][3]=fmaf(av.w,wv4.w,acc[3][3]);
    }
    __syncthreads();
#pragma unroll
    for (int i = 0; i < 4; ++i)
#pragma unroll
      for (int j = 0; j < 4; ++j){
        float y = acc[i][j] + bb4[j];
        vmn[j] = fminf(vmn[j], y); vmx[j] = fmaxf(vmx[j], y);
        ssum[j] += y; ssq[j] = fmaf(y, y, ssq[j]);
      }
  }
  float* scr = aT;   // 8192 floats scratch
#pragma unroll
  for (int j = 0; j < 4; ++j){
    scr[((0*16+rg)*16+cg)*4 + j] = vmn[j];
    scr[((1*16+rg)*16+cg)*4 + j] = vmx[j];
    scr[((2*16+rg)*16+cg)*4 + j] = ssum[j];
    scr[((3*16+rg)*16+cg)*4 + j] = ssq[j];
  }
  __syncthreads();
  if (tid < 64){
    int cg_ = tid >> 2, j_ = tid & 3;
    float mn = INFINITY, mx = -INFINITY, s = 0.f, q = 0.f;
    for (int r = 0; r < 16; ++r){
      mn = fminf(mn, scr[((0*16+r)*16+cg_)*4 + j_]);
      mx = fmaxf(mx, scr[((1*16+r)*16+cg_)*4 + j_]);
      s += scr[((2*16+r)*16+cg_)*4 + j_];
      q += scr[((3*16+r)*16+cg_)*4 + j_];
    }
    int c = c0 + cg_*4 + j_;
    atomicAdd(&stats2b[c], s);
    atomicAdd(&stats2b[256+c], q);
    atomicMaxF(&gmax[batch*256 + c], mx);
    atomicMinF(&gmin[batch*256 + c], mn);
  }
}

__global__ __launch_bounds__(256) void final_kernel(
    const float* __restrict__ stats2b, const unsigned* __restrict__ gmax,
    const unsigned* __restrict__ gmin, const float* __restrict__ g2b,
    const float* __restrict__ be2b, float* __restrict__ out){
  int t = blockIdx.x*256 + threadIdx.x;
  if (t >= NB*256) return;
  int c = t & 255;
  const float inv = 1.0f / (float)RC2;
  float mu = stats2b[c]*inv;
  float var = fmaxf(stats2b[256+c]*inv - mu*mu, 0.f);
  float sc = rsqrtf(var + 1e-5f)*g2b[c];
  float sh = be2b[c] - mu*sc;
  float mx = __uint_as_float(gmax[t]);
  float mn = __uint_as_float(gmin[t]);
  out[t] = fmaxf(silu_f(fmaf(mx, sc, sh)), silu_f(fmaf(mn, sc, sh)));
}

extern "C" void kernel_launch(void* const* d_in, const int* in_sizes, int n_in,
                              void* d_out, int out_size, void* d_ws, size_t ws_size,
                              hipStream_t stream){
  (void)in_sizes; (void)n_in; (void)out_size; (void)ws_size;
  const float* pos  = (const float*)d_in[0];
  const float* W1   = (const float*)d_in[1];
  const float* b1   = (const float*)d_in[2];
  const float* g1   = (const float*)d_in[3];
  const float* be1  = (const float*)d_in[4];
  const float* W2a  = (const float*)d_in[5];
  const float* b2a  = (const float*)d_in[6];
  const float* g2a  = (const float*)d_in[7];
  const float* be2a = (const float*)d_in[8];
  const float* W2b  = (const float*)d_in[9];
  const float* b2b  = (const float*)d_in[10];
  const float* g2b  = (const float*)d_in[11];
  const float* be2b = (const float*)d_in[12];

  char* w = (char*)d_ws;
  size_t off = 0;
  auto carve = [&](size_t bytes)->void*{ void* p = w + off; off += (bytes + 255) & ~(size_t)255; return p; };
  int*      idx1    = (int*)carve((size_t)NB*NN*KNNK*4);      // 2 MB
  float*    h       = (float*)carve((size_t)NB*NN*64*4);      // 8 MB
  int*      idxf    = (int*)carve((size_t)NB*MM*4);
  float*    pos2    = (float*)carve((size_t)NB*MM*3*4);
  int*      idx2    = (int*)carve((size_t)NB*MM*KNNK*4);      // 1 MB
  float*    stats1  = (float*)carve(128*4);
  float*    stats2a = (float*)carve(256*4);
  float*    stats2b = (float*)carve(512*4);
  unsigned* gmax    = (unsigned*)carve(4096*4);
  unsigned* gmin    = (unsigned*)carve(4096*4);
  __hip_bfloat16* y2a = (__hip_bfloat16*)carve((size_t)RC2*128*2);  // 64 MB
  // pknn buffers live inside the y2a region (dead before conv2a writes y2a)
  u64* pknn1 = (u64*)y2a;                          // 8 MB  (dead after K1)
  u64* pknn2 = (u64*)((char*)y2a + (32u<<20));     // 8 MB  (dead after K2)

  init_kernel<<<dim3(16), dim3(256), 0, stream>>>(stats1, stats2a, stats2b, gmax, gmin);
  k0_fps_knn1<<<dim3(272), dim3(256), 0, stream>>>(pos, idxf, pos2, pknn1);
  k1_merge1_knn2<<<dim3(384), dim3(256), 0, stream>>>(pknn1, idx1, pos2, pknn2);
  k2_merge2_c1stats<<<dim3(1088), dim3(256), 0, stream>>>(pknn2, idx2, pos, idx1, W1, b1, stats1);
  conv1_apply_kernel<<<dim3(1024), dim3(256), 0, stream>>>(pos, idx1, W1, b1, g1, be1, stats1, h);
  conv2a_kernel<<<dim3(1024), dim3(256), 0, stream>>>(h, idxf, pos2, idx2, W2a, b2a, stats2a, y2a);
  conv2b_kernel<<<dim3(2048), dim3(256), 0, stream>>>(y2a, stats2a, g2a, be2a, W2b, b2b, stats2b, gmax, gmin);
  final_kernel<<<dim3(16), dim3(256), 0, stream>>>(stats2b, gmax, gmin, g2b, be2b, (float*)d_out);
}